// Round 1
// baseline (351.688 us; speedup 1.0000x reference)
//
#include <hip/hip_runtime.h>

// AttnBlock: GN(32) -> 1x1 qkv -> full attention (B=2,C=512,N=4096) -> 1x1 proj -> +x
// All GEMMs in A*B^T form (both row-major [rows][K]) using the m97-verified structure:
// 128x128 tile, BK=32, 4 waves, 4x4 mfma_f32_16x16x32_bf16 per wave, global_load_lds(16B).

typedef unsigned short u16;
typedef unsigned int u32;
typedef __bf16 bf16x8 __attribute__((ext_vector_type(8)));
typedef float f32x4 __attribute__((ext_vector_type(4)));

#define NPOS 4096
#define CCH 512

__device__ __forceinline__ u16 f2bf(float f) {
  u32 u = __builtin_bit_cast(u32, f);
  u += 0x7fffu + ((u >> 16) & 1u);
  return (u16)(u >> 16);
}
__device__ __forceinline__ float bf2f(u16 h) {
  u32 u = ((u32)h) << 16;
  return __builtin_bit_cast(float, u);
}

__device__ __forceinline__ void load16_lds(const u16* g, u16* l) {
  __builtin_amdgcn_global_load_lds(
      (const __attribute__((address_space(1))) void*)g,
      (__attribute__((address_space(3))) void*)l, 16, 0, 0);
}

// ---------------- GroupNorm ----------------
__global__ __launch_bounds__(256) void gn_stats(const float* __restrict__ x,
                                                float2* __restrict__ stats) {
  int bg = blockIdx.x;  // b*32+g, reduces 16 ch * 4096 = 65536 contiguous floats
  const float4* p = (const float4*)(x + (size_t)bg * (16 * NPOS));
  float s = 0.f, s2 = 0.f;
  for (int i = threadIdx.x; i < 16384; i += 256) {
    float4 u = p[i];
    s += u.x + u.y + u.z + u.w;
    s2 += u.x * u.x + u.y * u.y + u.z * u.z + u.w * u.w;
  }
  for (int o = 32; o; o >>= 1) {
    s += __shfl_xor(s, o);
    s2 += __shfl_xor(s2, o);
  }
  __shared__ float rs[4], rq[4];
  int lane = threadIdx.x & 63, w = threadIdx.x >> 6;
  if (lane == 0) { rs[w] = s; rq[w] = s2; }
  __syncthreads();
  if (threadIdx.x == 0) {
    s = rs[0] + rs[1] + rs[2] + rs[3];
    s2 = rq[0] + rq[1] + rq[2] + rq[3];
    float mu = s * (1.f / 65536.f);
    float var = s2 * (1.f / 65536.f) - mu * mu;
    stats[bg] = make_float2(mu, rsqrtf(var + 1e-6f));
  }
}

// normalize + transpose: x[b][c][n] (f32) -> h_t[b][n][c] (bf16)
__global__ __launch_bounds__(256) void gn_apply(const float* __restrict__ x,
                                                const float* __restrict__ gnw,
                                                const float* __restrict__ gnb,
                                                const float2* __restrict__ stats,
                                                u16* __restrict__ h_t) {
  int b = blockIdx.z, c0 = blockIdx.y * 64, n0 = blockIdx.x * 64;
  __shared__ u16 lt[64][72];  // [n][c], pad to 72 so 8-elem rows stay 16B aligned
  const float* xb = x + (size_t)b * CCH * NPOS;
  int tid = threadIdx.x;
#pragma unroll
  for (int it = 0; it < 4; ++it) {
    int ci = (tid >> 4) + it * 16;
    int nj = (tid & 15) * 4;
    int c = c0 + ci;
    float4 v = *(const float4*)&xb[(size_t)c * NPOS + n0 + nj];
    float2 st = stats[b * 32 + (c >> 4)];
    float w = gnw[c] * st.y;
    float bb = gnb[c] - st.x * w;
    lt[nj + 0][ci] = f2bf(v.x * w + bb);
    lt[nj + 1][ci] = f2bf(v.y * w + bb);
    lt[nj + 2][ci] = f2bf(v.z * w + bb);
    lt[nj + 3][ci] = f2bf(v.w * w + bb);
  }
  __syncthreads();
#pragma unroll
  for (int it = 0; it < 2; ++it) {
    int ni = (tid >> 3) + it * 32;
    int cj = (tid & 7) * 8;
    uint4 o = *(const uint4*)&lt[ni][cj];
    *(uint4*)&h_t[((size_t)b * NPOS + n0 + ni) * CCH + c0 + cj] = o;
  }
}

// ---------------- weight f32 -> bf16 ----------------
__global__ __launch_bounds__(256) void wconv(const float* __restrict__ w0,
                                             const float* __restrict__ w1,
                                             const float* __restrict__ w2,
                                             const float* __restrict__ w3,
                                             u16* __restrict__ dst) {
  int which = blockIdx.y;
  const float* src = which == 0 ? w0 : which == 1 ? w1 : which == 2 ? w2 : w3;
  u16* d = dst + (size_t)which * (CCH * CCH);
  int i = blockIdx.x * 256 + threadIdx.x;  // 65536 float4 per matrix
  float4 v = ((const float4*)src)[i];
  uint2 o;
  o.x = (u32)f2bf(v.x) | ((u32)f2bf(v.y) << 16);
  o.y = (u32)f2bf(v.z) | ((u32)f2bf(v.w) << 16);
  ((uint2*)d)[i] = o;
}

// ---------------- GEMM: C[m,n] = alpha*(sum_k A[m,k]B[n,k] + bias) (+resid) ----------------
// BIAS_MODE: 0 none, 1 bias[n], 2 bias[m]
template <int BIAS_MODE, bool RESID, bool OUT_F32>
__global__ __launch_bounds__(256) void gemm_bt(const u16* __restrict__ A,
                                               const u16* __restrict__ Bm,
                                               void* __restrict__ Cv,
                                               const float* __restrict__ bias,
                                               const float* __restrict__ resid,
                                               float alpha, int M, int N, int K,
                                               long sA, long sB, long sC, long sR) {
  const int b = blockIdx.z;
  A += (size_t)b * sA;
  Bm += (size_t)b * sB;
  const int m0 = blockIdx.y * 128, n0 = blockIdx.x * 128;
  __shared__ u16 sAt[128 * 32];
  __shared__ u16 sBt[128 * 32];
  const int tid = threadIdx.x, wave = tid >> 6, lane = tid & 63;
  const int lrow = lane & 15, kch = lane >> 4;
  const int wm = (wave >> 1) * 64, wn = (wave & 1) * 64;
  const int srow = lane >> 2, skcol = (lane & 3) * 8;
  f32x4 acc[4][4] = {};

  for (int k0 = 0; k0 < K; k0 += 32) {
#pragma unroll
    for (int r = 0; r < 2; ++r) {
      int ch = wave * 2 + r;  // 16-row chunk of the 128-row tile
      const u16* ga = A + (size_t)(m0 + ch * 16 + srow) * K + (k0 + skcol);
      load16_lds(ga, sAt + ch * 512);
      const u16* gb = Bm + (size_t)(n0 + ch * 16 + srow) * K + (k0 + skcol);
      load16_lds(gb, sBt + ch * 512);
    }
    __syncthreads();
    bf16x8 af[4], bf[4];
#pragma unroll
    for (int i = 0; i < 4; ++i) {
      af[i] = *(const bf16x8*)(sAt + (wm + i * 16 + lrow) * 32 + kch * 8);
      bf[i] = *(const bf16x8*)(sBt + (wn + i * 16 + lrow) * 32 + kch * 8);
    }
#pragma unroll
    for (int i = 0; i < 4; ++i)
#pragma unroll
      for (int j = 0; j < 4; ++j)
        acc[i][j] = __builtin_amdgcn_mfma_f32_16x16x32_bf16(af[i], bf[j], acc[i][j], 0, 0, 0);
    __syncthreads();
  }

  const int col = lane & 15, rbase = (lane >> 4) * 4;
  const size_t cb = (size_t)b * sC;
#pragma unroll
  for (int i = 0; i < 4; ++i) {
    int mrow = m0 + wm + i * 16 + rbase;
#pragma unroll
    for (int j = 0; j < 4; ++j) {
      int ncol = n0 + wn + j * 16 + col;
      float bcol = (BIAS_MODE == 1) ? bias[ncol] : 0.f;
#pragma unroll
      for (int r = 0; r < 4; ++r) {
        int m = mrow + r;
        float v = acc[i][j][r];
        if (BIAS_MODE == 1) v += bcol;
        if (BIAS_MODE == 2) v += bias[m];
        v *= alpha;
        if (RESID) v += resid[(size_t)b * sR + (size_t)m * N + ncol];
        if (OUT_F32)
          ((float*)Cv)[cb + (size_t)m * N + ncol] = v;
        else
          ((u16*)Cv)[cb + (size_t)m * N + ncol] = f2bf(v);
      }
    }
  }
}

// ---------------- row softmax in place over 4096 bf16 ----------------
__global__ __launch_bounds__(256) void softmax_rows(u16* __restrict__ S) {
  const int row = blockIdx.x;
  u16* p = S + (size_t)row * NPOS;
  const int tid = threadIdx.x;
  uint4 d0 = ((const uint4*)p)[tid * 2];
  uint4 d1 = ((const uint4*)p)[tid * 2 + 1];
  float v[16];
  u32 w[8] = {d0.x, d0.y, d0.z, d0.w, d1.x, d1.y, d1.z, d1.w};
#pragma unroll
  for (int i = 0; i < 8; ++i) {
    v[2 * i] = bf2f((u16)(w[i] & 0xffff));
    v[2 * i + 1] = bf2f((u16)(w[i] >> 16));
  }
  float mx = -1e30f;
#pragma unroll
  for (int i = 0; i < 16; ++i) mx = fmaxf(mx, v[i]);
  for (int o = 32; o; o >>= 1) mx = fmaxf(mx, __shfl_xor(mx, o));
  __shared__ float red[4], red2[4];
  int lane = tid & 63, wv_ = tid >> 6;
  if (lane == 0) red[wv_] = mx;
  __syncthreads();
  mx = fmaxf(fmaxf(red[0], red[1]), fmaxf(red[2], red[3]));
  float s = 0.f;
#pragma unroll
  for (int i = 0; i < 16; ++i) {
    v[i] = __expf(v[i] - mx);
    s += v[i];
  }
  for (int o = 32; o; o >>= 1) s += __shfl_xor(s, o);
  if (lane == 0) red2[wv_] = s;
  __syncthreads();
  s = red2[0] + red2[1] + red2[2] + red2[3];
  float inv = 1.f / s;
#pragma unroll
  for (int i = 0; i < 8; ++i)
    w[i] = (u32)f2bf(v[2 * i] * inv) | ((u32)f2bf(v[2 * i + 1] * inv) << 16);
  uint4 o0 = {w[0], w[1], w[2], w[3]}, o1 = {w[4], w[5], w[6], w[7]};
  ((uint4*)p)[tid * 2] = o0;
  ((uint4*)p)[tid * 2 + 1] = o1;
}

extern "C" void kernel_launch(void* const* d_in, const int* in_sizes, int n_in,
                              void* d_out, int out_size, void* d_ws, size_t ws_size,
                              hipStream_t stream) {
  const float* x = (const float*)d_in[0];
  const float* gnw = (const float*)d_in[1];
  const float* gnb = (const float*)d_in[2];
  const float* wq = (const float*)d_in[3];
  const float* bq = (const float*)d_in[4];
  const float* wk = (const float*)d_in[5];
  const float* bk = (const float*)d_in[6];
  const float* wv = (const float*)d_in[7];
  const float* bv = (const float*)d_in[8];
  const float* wp = (const float*)d_in[9];
  const float* bp = (const float*)d_in[10];
  float* out = (float*)d_out;

  char* ws = (char*)d_ws;
  size_t off = 0;
  auto alloc = [&](size_t bytes) {
    void* p = ws + off;
    off += (bytes + 1023) & ~(size_t)1023;
    return p;
  };
  float2* stats = (float2*)alloc(64 * sizeof(float2));
  u16* wb = (u16*)alloc((size_t)4 * CCH * CCH * 2);  // wq|wk|wv|wp bf16
  u16* wqb = wb, *wkb = wb + CCH * CCH, *wvb = wb + 2 * CCH * CCH, *wpb = wb + 3 * CCH * CCH;
  u16* h_t = (u16*)alloc((size_t)2 * NPOS * CCH * 2);   // [b][n][c]
  u16* q_t = (u16*)alloc((size_t)2 * NPOS * CCH * 2);   // [b][n][d]
  u16* k_t = (u16*)alloc((size_t)2 * NPOS * CCH * 2);   // [b][n][d]
  u16* vbuf = (u16*)alloc((size_t)2 * CCH * NPOS * 2);  // [b][d][n]
  u16* o_t = (u16*)alloc((size_t)2 * NPOS * CCH * 2);   // [b][n][c]
  u16* Sb = (u16*)alloc((size_t)2 * NPOS * NPOS * 2);   // [b][nq][nk]

  const long sHC = (long)NPOS * CCH;
  const long sSS = (long)NPOS * NPOS;
  const float scale = 0.044194173824159216f;  // 512^-0.5

  gn_stats<<<64, 256, 0, stream>>>(x, stats);
  gn_apply<<<dim3(64, 8, 2), 256, 0, stream>>>(x, gnw, gnb, stats, h_t);
  wconv<<<dim3(256, 4), 256, 0, stream>>>(wq, wk, wv, wp, wb);
  // q_t[b][n][d] = scale*(h_t . wq^T + bq)
  gemm_bt<1, false, false><<<dim3(4, 32, 2), 256, 0, stream>>>(
      h_t, wqb, q_t, bq, nullptr, scale, NPOS, CCH, CCH, sHC, 0, sHC, 0);
  gemm_bt<1, false, false><<<dim3(4, 32, 2), 256, 0, stream>>>(
      h_t, wkb, k_t, bk, nullptr, 1.f, NPOS, CCH, CCH, sHC, 0, sHC, 0);
  // v[b][d][n] = wv . h_t^T + bv
  gemm_bt<2, false, false><<<dim3(32, 4, 2), 256, 0, stream>>>(
      wvb, h_t, vbuf, bv, nullptr, 1.f, CCH, NPOS, CCH, 0, sHC, sHC, 0);
  // S = q_t . k_t^T   (scale already folded into q)
  gemm_bt<0, false, false><<<dim3(32, 32, 2), 256, 0, stream>>>(
      q_t, k_t, Sb, nullptr, nullptr, 1.f, NPOS, NPOS, CCH, sHC, sHC, sSS, 0);
  softmax_rows<<<2 * NPOS, 256, 0, stream>>>(Sb);
  // O_t[b][nq][c] = P . v^T
  gemm_bt<0, false, false><<<dim3(4, 32, 2), 256, 0, stream>>>(
      Sb, vbuf, o_t, nullptr, nullptr, 1.f, NPOS, CCH, NPOS, sSS, sHC, sHC, 0);
  // out[b][d][n] = wp . o_t^T + bp + x
  gemm_bt<2, true, true><<<dim3(32, 4, 2), 256, 0, stream>>>(
      wpb, o_t, out, bp, x, 1.f, CCH, NPOS, CCH, 0, sHC, sHC, sHC);
}